// Round 10
// baseline (497.332 us; speedup 1.0000x reference)
//
#include <hip/hip_runtime.h>
#include <math.h>

#define N 8192
#define D 512
#define KSEL 5
#define TEMP_INV 10.0f
#define MARGIN 0.012f
#define CCAP 64
#define BK 64
#define CPITCH 136  // LDS C-stage pitch in shorts (R5-proven)
#define NSTRIP 128  // 64-col strips per row
#define NTILE 64
#define NBLK (NTILE * (NTILE + 1) / 2)  // 2080 upper-triangle tiles

using short8 = __attribute__((ext_vector_type(8))) short;
using floatx4 = __attribute__((ext_vector_type(4))) float;

// Lexicographic top-5 insert: (value desc, index asc) — matches lax.top_k.
#define INS(TV, TIX, RI, VV, JJ)                                                     \
  {                                                                                  \
    const float _v = (VV);                                                           \
    const int _j = (JJ);                                                             \
    const bool _b4 = (_v > TV[RI][4]) || (_v == TV[RI][4] && _j < TIX[RI][4]);       \
    if (_b4) {                                                                       \
      const bool _b0 = (_v > TV[RI][0]) || (_v == TV[RI][0] && _j < TIX[RI][0]);     \
      const bool _b1 = (_v > TV[RI][1]) || (_v == TV[RI][1] && _j < TIX[RI][1]);     \
      const bool _b2 = (_v > TV[RI][2]) || (_v == TV[RI][2] && _j < TIX[RI][2]);     \
      const bool _b3 = (_v > TV[RI][3]) || (_v == TV[RI][3] && _j < TIX[RI][3]);     \
      TV[RI][4] = _b3 ? TV[RI][3] : _v;                                              \
      TIX[RI][4] = _b3 ? TIX[RI][3] : _j;                                            \
      TV[RI][3] = _b2 ? TV[RI][2] : (_b3 ? _v : TV[RI][3]);                          \
      TIX[RI][3] = _b2 ? TIX[RI][2] : (_b3 ? _j : TIX[RI][3]);                       \
      TV[RI][2] = _b1 ? TV[RI][1] : (_b2 ? _v : TV[RI][2]);                          \
      TIX[RI][2] = _b1 ? TIX[RI][1] : (_b2 ? _j : TIX[RI][2]);                       \
      TV[RI][1] = _b0 ? TV[RI][0] : (_b1 ? _v : TV[RI][1]);                          \
      TIX[RI][1] = _b0 ? TIX[RI][0] : (_b1 ? _j : TIX[RI][1]);                       \
      TV[RI][0] = _b0 ? _v : TV[RI][0];                                              \
      TIX[RI][0] = _b0 ? _j : TIX[RI][0];                                            \
    }                                                                                \
  }

__device__ inline unsigned short f2b(float f) {  // fp32 -> bf16 RNE (monotone)
    unsigned int u = __float_as_uint(f);
    unsigned int r = (u + 0x7FFFu + ((u >> 16) & 1u)) >> 16;
    return (unsigned short)r;
}
__device__ inline float b2f(unsigned short u) {
    return __uint_as_float(((unsigned int)u) << 16);
}

__device__ inline void gload_lds16(const unsigned short* g, unsigned short* l) {
    __builtin_amdgcn_global_load_lds((__attribute__((address_space(1))) void*)g,
                                     (__attribute__((address_space(3))) void*)l, 16, 0, 0);
}

// ---------------- Kernel 1: norms + bf16 normalized rows -----------------
__global__ __launch_bounds__(64) void prep_kernel(const float* __restrict__ X,
                                                  unsigned short* __restrict__ Xb,
                                                  float* __restrict__ inv) {
    const int row = blockIdx.x;
    const int t = threadIdx.x;
    const float4* xr = (const float4*)(X + (size_t)row * D);
    const float4 a = xr[t];
    const float4 b = xr[t + 64];
    float ss = a.x * a.x + a.y * a.y + a.z * a.z + a.w * a.w +
               b.x * b.x + b.y * b.y + b.z * b.z + b.w * b.w;
#pragma unroll
    for (int off = 32; off > 0; off >>= 1) ss += __shfl_xor(ss, off, 64);
    const float iv = 1.0f / fmaxf(sqrtf(ss), 1e-12f);
    if (t == 0) inv[row] = iv;
    ushort4 ua, ub;
    ua.x = f2b(a.x * iv); ua.y = f2b(a.y * iv); ua.z = f2b(a.z * iv); ua.w = f2b(a.w * iv);
    ub.x = f2b(b.x * iv); ub.y = f2b(b.y * iv); ub.z = f2b(b.z * iv); ub.w = f2b(b.w * iv);
    ((ushort4*)(Xb + (size_t)row * D))[t] = ua;
    ((ushort4*)(Xb + (size_t)row * D))[t + 64] = ub;
}

// ---------------- Kernel 2: symmetric MFMA GEMM -> strip top-5 lists -----
// Upper-triangle tile per block. NO C matrix is written: the epilogue
// stages the tile in LDS once and extracts per-(row,strip) top-5 packed
// entries (bf16val<<16 | colidx) for both orientations, plus strip maxima.
// Tail zero-fills the final output slice.
__global__ __launch_bounds__(256) void gemm_kernel(const unsigned short* __restrict__ Xb,
                                                   unsigned short* __restrict__ rowmaxG,
                                                   unsigned int* __restrict__ lists,
                                                   float* __restrict__ outz) {
    __shared__ unsigned short smem[128 * CPITCH];  // 34.8 KB (A|B 32 KB, then Cs)
    unsigned short* Asm = smem;
    unsigned short* Bsm = smem + 8192;
    const int tid = threadIdx.x;
    const int w = tid >> 6;
    const int lane = tid & 63;
    const int wr = w >> 1, wc = w & 1;

    // decode upper-triangle pair: off(ti) = ti*(129-ti)/2
    const int t = (int)blockIdx.x;
    int tib = (int)((129.0 - sqrt(129.0 * 129.0 - 8.0 * (double)t)) * 0.5);
    while ((tib + 1) * (129 - (tib + 1)) / 2 <= t) ++tib;
    while (tib * (129 - tib) / 2 > t) --tib;
    const int tjb = tib + (t - tib * (129 - tib) / 2);
    const int i0 = tib * 128, j0 = tjb * 128;

    floatx4 acc[4][4];
#pragma unroll
    for (int ti = 0; ti < 4; ++ti)
#pragma unroll
        for (int tj = 0; tj < 4; ++tj) acc[ti][tj] = (floatx4){0.f, 0.f, 0.f, 0.f};

    const unsigned short* gA[4];
    const unsigned short* gB[4];
    unsigned short* lA[4];
    unsigned short* lB[4];
#pragma unroll
    for (int p = 0; p < 4; ++p) {
        const int slot = p * 256 + tid;
        const int row = slot >> 3;
        const int kq = (slot & 7) ^ (row & 7);
        gA[p] = Xb + (size_t)(i0 + row) * D + kq * 8;
        gB[p] = Xb + (size_t)(j0 + row) * D + kq * 8;
        lA[p] = Asm + slot * 8;
        lB[p] = Bsm + slot * 8;
    }

    const int r = lane & 15;
    const int q = lane >> 4;
    const int aRow0 = wr * 64 + r;
    const int bRow0 = wc * 64 + r;
    const int rx = r & 7;

#pragma unroll
    for (int p = 0; p < 4; ++p) {
        gload_lds16(gA[p], lA[p]);
        gload_lds16(gB[p], lB[p]);
    }

    for (int kc = 0; kc < D / BK; ++kc) {
        __syncthreads();
        short8 af[2][4], bf[2][4];
#pragma unroll
        for (int tt = 0; tt < 2; ++tt)
#pragma unroll
            for (int ti = 0; ti < 4; ++ti) {
                af[tt][ti] = *(const short8*)(Asm +
                    ((aRow0 + ti * 16) * 8 + ((tt * 4 + q) ^ rx)) * 8);
                bf[tt][ti] = *(const short8*)(Bsm +
                    ((bRow0 + ti * 16) * 8 + ((tt * 4 + q) ^ rx)) * 8);
            }
        __syncthreads();
        if (kc < D / BK - 1) {
            const int o = (kc + 1) * BK;
#pragma unroll
            for (int p = 0; p < 4; ++p) {
                gload_lds16(gA[p] + o, lA[p]);
                gload_lds16(gB[p] + o, lB[p]);
            }
        }
#pragma unroll
        for (int tt = 0; tt < 2; ++tt)
#pragma unroll
            for (int ti = 0; ti < 4; ++ti)
#pragma unroll
                for (int tj = 0; tj < 4; ++tj)
                    acc[ti][tj] = __builtin_amdgcn_mfma_f32_16x16x32_bf16(
                        af[tt][ti], bf[tt][tj], acc[ti][tj], 0, 0, 0);
    }

    // ---- A-side strip maxima: rows i0.., strip tjb*2 + wc ----
    {
        float rmax[16];
#pragma unroll
        for (int ti = 0; ti < 4; ++ti)
#pragma unroll
            for (int reg = 0; reg < 4; ++reg) {
                const float m0 = fmaxf(acc[ti][0][reg], acc[ti][1][reg]);
                const float m1 = fmaxf(acc[ti][2][reg], acc[ti][3][reg]);
                rmax[ti * 4 + reg] = fmaxf(m0, m1);
            }
#pragma unroll
        for (int k = 0; k < 16; ++k)
#pragma unroll
            for (int m = 1; m < 16; m <<= 1)
                rmax[k] = fmaxf(rmax[k], __shfl_xor(rmax[k], m, 64));
        if (r == 0) {
            const int strip = tjb * 2 + wc;
#pragma unroll
            for (int ti = 0; ti < 4; ++ti)
#pragma unroll
                for (int reg = 0; reg < 4; ++reg)
                    rowmaxG[(size_t)(i0 + wr * 64 + ti * 16 + q * 4 + reg) * NSTRIP +
                            strip] = f2b(rmax[ti * 4 + reg]);
        }
    }

    // ---- B-side strip maxima (mirror): rows j0.., strip tib*2 + wr ----
    if (tib != tjb) {
        float cmax[4];
#pragma unroll
        for (int tj = 0; tj < 4; ++tj) {
            float m = -1e30f;
#pragma unroll
            for (int ti = 0; ti < 4; ++ti)
#pragma unroll
                for (int reg = 0; reg < 4; ++reg) m = fmaxf(m, acc[ti][tj][reg]);
            m = fmaxf(m, __shfl_xor(m, 16, 64));
            m = fmaxf(m, __shfl_xor(m, 32, 64));
            cmax[tj] = m;
        }
        if (q == 0) {
#pragma unroll
            for (int tj = 0; tj < 4; ++tj)
                rowmaxG[(size_t)(j0 + wc * 64 + tj * 16 + r) * NSTRIP + tib * 2 + wr] =
                    f2b(cmax[tj]);
        }
    }

    // ---- stage tile once in LDS (bf16, xor-swizzled cols) ----
    __syncthreads();  // frag reads done; smem reused as Cs
    unsigned short* Cs = smem;
#pragma unroll
    for (int ti = 0; ti < 4; ++ti)
#pragma unroll
        for (int tj = 0; tj < 4; ++tj)
#pragma unroll
            for (int reg = 0; reg < 4; ++reg) {
                const int rowl = wr * 64 + ti * 16 + q * 4 + reg;
                const int coll = wc * 64 + tj * 16 + r;
                Cs[rowl * CPITCH + (coll ^ ((rowl & 7) << 3))] = f2b(acc[ti][tj][reg]);
            }
    __syncthreads();

    // ---- A-side top-5 lists: thread = (row, strip-half) ----
    {
        const int rowl = tid & 127;
        const int sh = tid >> 7;
        const int xorv = rowl & 7;
        float tv[1][5];
        int tix[1][5];
#pragma unroll
        for (int s = 0; s < 5; ++s) { tv[0][s] = -1e30f; tix[0][s] = 0x7fffffff; }
#pragma unroll
        for (int q8 = 0; q8 < 8; ++q8) {
            const short8 v = *(const short8*)&Cs[rowl * CPITCH + (sh * 8 + q8) * 8];
            const int jc = j0 + sh * 64 + (q8 ^ xorv) * 8;
#pragma unroll
            for (int e = 0; e < 8; ++e) INS(tv, tix, 0, b2f((unsigned short)v[e]), jc + e);
        }
        unsigned int* dst = lists + ((size_t)(i0 + rowl) * NSTRIP + (tjb * 2 + sh)) * 5;
#pragma unroll
        for (int s = 0; s < 5; ++s)
            dst[s] = ((unsigned int)f2b(tv[0][s]) << 16) | (unsigned int)(tix[0][s] & 0xFFFF);
    }

    // ---- mirror top-5 lists: thread = (col, row-strip-half) ----
    if (tib != tjb) {
        const int cl = tid & 127;
        const int sh = tid >> 7;
        float tv[1][5];
        int tix[1][5];
#pragma unroll
        for (int s = 0; s < 5; ++s) { tv[0][s] = -1e30f; tix[0][s] = 0x7fffffff; }
        for (int k = 0; k < 64; ++k) {
            const int rr = sh * 64 + k;
            const unsigned short v = Cs[rr * CPITCH + (cl ^ ((rr & 7) << 3))];
            INS(tv, tix, 0, b2f(v), i0 + rr);
        }
        unsigned int* dst = lists + ((size_t)(j0 + cl) * NSTRIP + (tib * 2 + sh)) * 5;
#pragma unroll
        for (int s = 0; s < 5; ++s)
            dst[s] = ((unsigned int)f2b(tv[0][s]) << 16) | (unsigned int)(tix[0][s] & 0xFFFF);
    }

    // ---- tail: zero-fill this block's slice of the final output ----
    {
        const size_t total4 = (size_t)N * N / 4;
        const size_t per = (total4 + NBLK - 1) / NBLK;
        const size_t beg = (size_t)blockIdx.x * per;
        const size_t end = (beg + per < total4) ? beg + per : total4;
        float4* o4 = (float4*)outz;
        const float4 z = make_float4(0.f, 0.f, 0.f, 0.f);
        for (size_t idx = beg + tid; idx < end; idx += 256) o4[idx] = z;
    }
}

// ---------------- Kernel 3: list-guided candidates + rescore + scatter ---
// Wave w of block b owns row 4b+w. Candidates come from stored top-5 lists
// of strips above threshold; a strip whose stored 5th >= thr is recomputed
// exactly in fp32 (rare fallback, guarantees the superset).
__global__ __launch_bounds__(256) void scanfin_kernel(const unsigned int* __restrict__ lists,
                                                      const unsigned short* __restrict__ rowmaxG,
                                                      const float* __restrict__ X,
                                                      const float* __restrict__ inv,
                                                      float* __restrict__ out) {
    __shared__ int acnt[4];
    __shared__ int alist[4][NSTRIP];
    __shared__ int fcnt[4];
    __shared__ int flist[4][NSTRIP];
    __shared__ int scnt[4];
    __shared__ int sci[4][CCAP];
    __shared__ float xrow[4][D];
    const int tid = threadIdx.x;
    const int w = tid >> 6;
    const int lane = tid & 63;
    const int row = (int)blockIdx.x * 4 + w;
    if (lane == 0) { acnt[w] = 0; fcnt[w] = 0; scnt[w] = 0; }
    __syncthreads();

    // stage X[row] (fp32) for rescore/fallback
    const float4* xr = (const float4*)(X + (size_t)row * D);
    const float4 xa = xr[lane * 2];
    const float4 xb = xr[lane * 2 + 1];
    ((float4*)xrow[w])[lane * 2] = xa;
    ((float4*)xrow[w])[lane * 2 + 1] = xb;

    // m5 = 5th-largest strip max (wave-reduce over 128 bf16 strip maxes)
    const ushort2 su = *(const ushort2*)(rowmaxG + (size_t)row * NSTRIP + lane * 2);
    const float s0v = b2f(su.x), s1v = b2f(su.y);
    float a = s0v, b = s1v;
    float m5 = -1e30f;
#pragma unroll
    for (int s = 0; s < 5; ++s) {
        float mx = fmaxf(a, b);
#pragma unroll
        for (int m = 32; m > 0; m >>= 1) mx = fmaxf(mx, __shfl_xor(mx, m, 64));
        m5 = mx;
        const unsigned long long msk = __ballot(a == mx || b == mx);
        const int first = __ffsll(msk) - 1;
        if (lane == first) {
            if (a == mx) a = -1e30f;
            else b = -1e30f;
        }
    }
    const float thr = m5 - MARGIN;

    // select strips
    if (s0v >= thr) { const int p = atomicAdd(&acnt[w], 1); alist[w][p] = lane * 2; }
    if (s1v >= thr) { const int p = atomicAdd(&acnt[w], 1); alist[w][p] = lane * 2 + 1; }
    const int na = acnt[w];

    // fallback detection: stored 5th >= thr means list may be incomplete
    for (int g = lane; g < na; g += 64) {
        const int s = alist[w][g];
        const unsigned int p4 = lists[((size_t)row * NSTRIP + s) * 5 + 4];
        if (b2f((unsigned short)(p4 >> 16)) >= thr) {
            const int fp = atomicAdd(&fcnt[w], 1);
            flist[w][fp] = s;
            alist[w][g] = -1;
        }
    }

    // stored candidates from complete strips
    for (int e = lane; e < na * 5; e += 64) {
        const int g = e / 5;
        const int s = alist[w][g];
        if (s >= 0) {
            const unsigned int p = lists[((size_t)row * NSTRIP + s) * 5 + (e - g * 5)];
            if (b2f((unsigned short)(p >> 16)) >= thr) {
                const int cp = atomicAdd(&scnt[w], 1);
                if (cp < CCAP) sci[w][cp] = (int)(p & 0xFFFF);
            }
        }
    }

    // fallback strips: exact fp32 full-strip scan (rare)
    const float myinv = inv[row];
    const int nf = fcnt[w];
    for (int f = 0; f < nf; ++f) {
        const int s = flist[w][f];
        const int jg = s * 64 + lane;
        const float4* yr = (const float4*)(X + (size_t)jg * D);
        float dot = 0.f;
        for (int k4 = 0; k4 < D / 4; ++k4) {
            const float4 xa4 = ((const float4*)xrow[w])[k4];
            const float4 ya4 = yr[k4];
            dot += xa4.x * ya4.x + xa4.y * ya4.y + xa4.z * ya4.z + xa4.w * ya4.w;
        }
        const float val = dot * myinv * inv[jg];
        if (val >= thr) {
            const int cp = atomicAdd(&scnt[w], 1);
            if (cp < CCAP) sci[w][cp] = jg;
        }
    }
    int nc = scnt[w];
    if (nc > CCAP) nc = CCAP;

    // exact fp32 rescore + lexicographic top-5
    float ev[1][5];
    int ei[1][5];
#pragma unroll
    for (int s = 0; s < 5; ++s) { ev[0][s] = -1e30f; ei[0][s] = 0x7fffffff; }
    for (int c = 0; c < nc; ++c) {
        const int cj = sci[w][c];
        const float4* yr = (const float4*)(X + (size_t)cj * D);
        const float4 ya = yr[lane * 2];
        const float4 yb = yr[lane * 2 + 1];
        float p = xa.x * ya.x + xa.y * ya.y + xa.z * ya.z + xa.w * ya.w +
                  xb.x * yb.x + xb.y * yb.y + xb.z * yb.z + xb.w * yb.w;
#pragma unroll
        for (int off = 32; off > 0; off >>= 1) p += __shfl_xor(p, off, 64);
        const float val = p * myinv * inv[cj];
        INS(ev, ei, 0, val, cj);
    }

    if (lane == 0) {
        float e[KSEL];
        float sum = 0.f;
#pragma unroll
        for (int s = 0; s < KSEL; ++s) {
            e[s] = expf((ev[0][s] - ev[0][0]) * TEMP_INV);
            sum += e[s];
        }
        const float invs = 1.0f / sum;
#pragma unroll
        for (int s = 0; s < KSEL; ++s) {
            const int ix = ei[0][s];
            if (ix >= 0 && ix < N) out[(size_t)row * N + ix] = e[s] * invs;
        }
    }
}

extern "C" void kernel_launch(void* const* d_in, const int* in_sizes, int n_in,
                              void* d_out, int out_size, void* d_ws, size_t ws_size,
                              hipStream_t stream) {
    const float* X = (const float*)d_in[0];
    float* out = (float*)d_out;
    // ws: Xb bf16 [8 MB] | inv [32 KB] | rowmax bf16 [2 MB] | lists u32 [21 MB @ +16 MB]
    unsigned short* Xb = (unsigned short*)d_ws;
    float* inv = (float*)(Xb + (size_t)N * D);
    unsigned short* rowmaxG = (unsigned short*)(inv + N);
    unsigned int* lists = (unsigned int*)((char*)d_ws + (16u << 20));

    hipLaunchKernelGGL(prep_kernel, dim3(N), dim3(64), 0, stream, X, Xb, inv);
    hipLaunchKernelGGL(gemm_kernel, dim3(NBLK), dim3(256), 0, stream, Xb, rowmaxG, lists, out);
    hipLaunchKernelGGL(scanfin_kernel, dim3(N / 4), dim3(256), 0, stream, lists, rowmaxG, X,
                       inv, out);
}

// Round 11
// 430.094 us; speedup vs baseline: 1.1563x; 1.1563x over previous
//
#include <hip/hip_runtime.h>
#include <math.h>

#define N 8192
#define D 512
#define KSEL 5
#define TEMP_INV 10.0f
#define MARGIN 0.012f
#define CCAP 64
#define BK 64
#define CPITCH 136  // LDS C-stage pitch in shorts (R5-proven)
#define NSTRIP 128  // 64-col strips per row
#define NTILE 64
#define NBLK (NTILE * (NTILE + 1) / 2)  // 2080 upper-triangle tiles

using short8 = __attribute__((ext_vector_type(8))) short;
using floatx4 = __attribute__((ext_vector_type(4))) float;

// Lexicographic top-5 insert: (value desc, index asc) — matches lax.top_k.
#define INS(TV, TIX, RI, VV, JJ)                                                     \
  {                                                                                  \
    const float _v = (VV);                                                           \
    const int _j = (JJ);                                                             \
    const bool _b4 = (_v > TV[RI][4]) || (_v == TV[RI][4] && _j < TIX[RI][4]);       \
    if (_b4) {                                                                       \
      const bool _b0 = (_v > TV[RI][0]) || (_v == TV[RI][0] && _j < TIX[RI][0]);     \
      const bool _b1 = (_v > TV[RI][1]) || (_v == TV[RI][1] && _j < TIX[RI][1]);     \
      const bool _b2 = (_v > TV[RI][2]) || (_v == TV[RI][2] && _j < TIX[RI][2]);     \
      const bool _b3 = (_v > TV[RI][3]) || (_v == TV[RI][3] && _j < TIX[RI][3]);     \
      TV[RI][4] = _b3 ? TV[RI][3] : _v;                                              \
      TIX[RI][4] = _b3 ? TIX[RI][3] : _j;                                            \
      TV[RI][3] = _b2 ? TV[RI][2] : (_b3 ? _v : TV[RI][3]);                          \
      TIX[RI][3] = _b2 ? TIX[RI][2] : (_b3 ? _j : TIX[RI][3]);                       \
      TV[RI][2] = _b1 ? TV[RI][1] : (_b2 ? _v : TV[RI][2]);                          \
      TIX[RI][2] = _b1 ? TIX[RI][1] : (_b2 ? _j : TIX[RI][2]);                       \
      TV[RI][1] = _b0 ? TV[RI][0] : (_b1 ? _v : TV[RI][1]);                          \
      TIX[RI][1] = _b0 ? TIX[RI][0] : (_b1 ? _j : TIX[RI][1]);                       \
      TV[RI][0] = _b0 ? _v : TV[RI][0];                                              \
      TIX[RI][0] = _b0 ? _j : TIX[RI][0];                                            \
    }                                                                                \
  }

__device__ inline unsigned short f2b(float f) {  // fp32 -> bf16 RNE (monotone)
    unsigned int u = __float_as_uint(f);
    unsigned int r = (u + 0x7FFFu + ((u >> 16) & 1u)) >> 16;
    return (unsigned short)r;
}
__device__ inline float b2f(unsigned short u) {
    return __uint_as_float(((unsigned int)u) << 16);
}

__device__ inline void gload_lds16(const unsigned short* g, unsigned short* l) {
    __builtin_amdgcn_global_load_lds((__attribute__((address_space(1))) void*)g,
                                     (__attribute__((address_space(3))) void*)l, 16, 0, 0);
}

// ---------------- Kernel 1: norms + bf16 normalized rows -----------------
__global__ __launch_bounds__(64) void prep_kernel(const float* __restrict__ X,
                                                  unsigned short* __restrict__ Xb,
                                                  float* __restrict__ inv) {
    const int row = blockIdx.x;
    const int t = threadIdx.x;
    const float4* xr = (const float4*)(X + (size_t)row * D);
    const float4 a = xr[t];
    const float4 b = xr[t + 64];
    float ss = a.x * a.x + a.y * a.y + a.z * a.z + a.w * a.w +
               b.x * b.x + b.y * b.y + b.z * b.z + b.w * b.w;
#pragma unroll
    for (int off = 32; off > 0; off >>= 1) ss += __shfl_xor(ss, off, 64);
    const float iv = 1.0f / fmaxf(sqrtf(ss), 1e-12f);
    if (t == 0) inv[row] = iv;
    ushort4 ua, ub;
    ua.x = f2b(a.x * iv); ua.y = f2b(a.y * iv); ua.z = f2b(a.z * iv); ua.w = f2b(a.w * iv);
    ub.x = f2b(b.x * iv); ub.y = f2b(b.y * iv); ub.z = f2b(b.z * iv); ub.w = f2b(b.w * iv);
    ((ushort4*)(Xb + (size_t)row * D))[t] = ua;
    ((ushort4*)(Xb + (size_t)row * D))[t + 64] = ub;
}

// ---------------- Kernel 2: symmetric bf16 MFMA GEMM (upper C only) ------
// Upper-triangle tile (tib <= tjb) per block; writes ONLY its own tile
// (no mirror — scanfin reads lower strips via transposed gather), strip
// maxima for both orientations, then zero-fills its output slice.
__global__ __launch_bounds__(256) void gemm_kernel(const unsigned short* __restrict__ Xb,
                                                   unsigned short* __restrict__ Cout,
                                                   unsigned short* __restrict__ rowmaxG,
                                                   float* __restrict__ outz) {
    __shared__ unsigned short smem[128 * CPITCH];  // 34.8 KB (A|B 32 KB, then Cs)
    unsigned short* Asm = smem;
    unsigned short* Bsm = smem + 8192;
    const int tid = threadIdx.x;
    const int w = tid >> 6;
    const int lane = tid & 63;
    const int wr = w >> 1, wc = w & 1;

    // decode upper-triangle pair: off(ti) = ti*(129-ti)/2
    const int t = (int)blockIdx.x;
    int tib = (int)((129.0 - sqrt(129.0 * 129.0 - 8.0 * (double)t)) * 0.5);
    while ((tib + 1) * (129 - (tib + 1)) / 2 <= t) ++tib;
    while (tib * (129 - tib) / 2 > t) --tib;
    const int tjb = tib + (t - tib * (129 - tib) / 2);
    const int i0 = tib * 128, j0 = tjb * 128;

    floatx4 acc[4][4];
#pragma unroll
    for (int ti = 0; ti < 4; ++ti)
#pragma unroll
        for (int tj = 0; tj < 4; ++tj) acc[ti][tj] = (floatx4){0.f, 0.f, 0.f, 0.f};

    const unsigned short* gA[4];
    const unsigned short* gB[4];
    unsigned short* lA[4];
    unsigned short* lB[4];
#pragma unroll
    for (int p = 0; p < 4; ++p) {
        const int slot = p * 256 + tid;
        const int row = slot >> 3;
        const int kq = (slot & 7) ^ (row & 7);
        gA[p] = Xb + (size_t)(i0 + row) * D + kq * 8;
        gB[p] = Xb + (size_t)(j0 + row) * D + kq * 8;
        lA[p] = Asm + slot * 8;
        lB[p] = Bsm + slot * 8;
    }

    const int r = lane & 15;
    const int q = lane >> 4;
    const int aRow0 = wr * 64 + r;
    const int bRow0 = wc * 64 + r;
    const int rx = r & 7;

#pragma unroll
    for (int p = 0; p < 4; ++p) {
        gload_lds16(gA[p], lA[p]);
        gload_lds16(gB[p], lB[p]);
    }

    for (int kc = 0; kc < D / BK; ++kc) {
        __syncthreads();
        short8 af[2][4], bf[2][4];
#pragma unroll
        for (int tt = 0; tt < 2; ++tt)
#pragma unroll
            for (int ti = 0; ti < 4; ++ti) {
                af[tt][ti] = *(const short8*)(Asm +
                    ((aRow0 + ti * 16) * 8 + ((tt * 4 + q) ^ rx)) * 8);
                bf[tt][ti] = *(const short8*)(Bsm +
                    ((bRow0 + ti * 16) * 8 + ((tt * 4 + q) ^ rx)) * 8);
            }
        __syncthreads();
        if (kc < D / BK - 1) {
            const int o = (kc + 1) * BK;
#pragma unroll
            for (int p = 0; p < 4; ++p) {
                gload_lds16(gA[p] + o, lA[p]);
                gload_lds16(gB[p] + o, lB[p]);
            }
        }
#pragma unroll
        for (int tt = 0; tt < 2; ++tt)
#pragma unroll
            for (int ti = 0; ti < 4; ++ti)
#pragma unroll
                for (int tj = 0; tj < 4; ++tj)
                    acc[ti][tj] = __builtin_amdgcn_mfma_f32_16x16x32_bf16(
                        af[tt][ti], bf[tt][tj], acc[ti][tj], 0, 0, 0);
    }

    // ---- A-side strip maxima: rows i0.., strip tjb*2 + wc ----
    {
        float rmax[16];
#pragma unroll
        for (int ti = 0; ti < 4; ++ti)
#pragma unroll
            for (int reg = 0; reg < 4; ++reg) {
                const float m0 = fmaxf(acc[ti][0][reg], acc[ti][1][reg]);
                const float m1 = fmaxf(acc[ti][2][reg], acc[ti][3][reg]);
                rmax[ti * 4 + reg] = fmaxf(m0, m1);
            }
#pragma unroll
        for (int k = 0; k < 16; ++k)
#pragma unroll
            for (int m = 1; m < 16; m <<= 1)
                rmax[k] = fmaxf(rmax[k], __shfl_xor(rmax[k], m, 64));
        if (r == 0) {
            const int strip = tjb * 2 + wc;
#pragma unroll
            for (int ti = 0; ti < 4; ++ti)
#pragma unroll
                for (int reg = 0; reg < 4; ++reg)
                    rowmaxG[(size_t)(i0 + wr * 64 + ti * 16 + q * 4 + reg) * NSTRIP +
                            strip] = f2b(rmax[ti * 4 + reg]);
        }
    }

    // ---- B-side strip maxima (mirror rows): rows j0.., strip tib*2 + wr --
    if (tib != tjb) {
        float cmax[4];
#pragma unroll
        for (int tj = 0; tj < 4; ++tj) {
            float m = -1e30f;
#pragma unroll
            for (int ti = 0; ti < 4; ++ti)
#pragma unroll
                for (int reg = 0; reg < 4; ++reg) m = fmaxf(m, acc[ti][tj][reg]);
            m = fmaxf(m, __shfl_xor(m, 16, 64));
            m = fmaxf(m, __shfl_xor(m, 32, 64));
            cmax[tj] = m;
        }
        if (q == 0) {
#pragma unroll
            for (int tj = 0; tj < 4; ++tj)
                rowmaxG[(size_t)(j0 + wc * 64 + tj * 16 + r) * NSTRIP + tib * 2 + wr] =
                    f2b(cmax[tj]);
        }
    }

    // ---- epilogue: LDS restage -> coalesced bf16 C write (own tile only) -
    __syncthreads();
    unsigned short* Cs = smem;
#pragma unroll
    for (int ti = 0; ti < 4; ++ti)
#pragma unroll
        for (int tj = 0; tj < 4; ++tj)
#pragma unroll
            for (int reg = 0; reg < 4; ++reg) {
                const int rowl = wr * 64 + ti * 16 + q * 4 + reg;
                const int coll = wc * 64 + tj * 16 + r;
                Cs[rowl * CPITCH + (coll ^ ((rowl & 7) << 3))] = f2b(acc[ti][tj][reg]);
            }
    __syncthreads();
#pragma unroll
    for (int p = 0; p < 8; ++p) {
        const int id = p * 256 + tid;
        const int rw = id >> 4;
        const int c = id & 15;
        const int cc = c ^ (rw & 7);
        const int4 v = *(const int4*)&Cs[rw * CPITCH + cc * 8];
        *(int4*)&Cout[(size_t)(i0 + rw) * N + j0 + c * 8] = v;
    }

    // ---- tail: zero-fill this block's slice of the final output ----
    {
        const size_t total4 = (size_t)N * N / 4;
        const size_t per = (total4 + NBLK - 1) / NBLK;
        const size_t beg = (size_t)blockIdx.x * per;
        const size_t end = (beg + per < total4) ? beg + per : total4;
        float4* o4 = (float4*)outz;
        const float4 z = make_float4(0.f, 0.f, 0.f, 0.f);
        for (size_t idx = beg + tid; idx < end; idx += 256) o4[idx] = z;
    }
}

// ---------------- Kernel 3: stripmax-guided candidates + rescore + out ---
// Wave w of block b owns row 4b+w. Upper strips read contiguous from
// C[row][..]; lower strips via symmetric transposed gather C[j][row]
// (identical stored values — same acc, same f2b).
__global__ __launch_bounds__(256) void scanfin_kernel(const unsigned short* __restrict__ C,
                                                      const unsigned short* __restrict__ rowmaxG,
                                                      const float* __restrict__ X,
                                                      const float* __restrict__ inv,
                                                      float* __restrict__ out) {
    __shared__ int acnt[4];
    __shared__ int alist[4][NSTRIP];
    __shared__ int scnt[4];
    __shared__ int sci[4][CCAP];
    const int tid = threadIdx.x;
    const int w = tid >> 6;
    const int lane = tid & 63;
    const int row = (int)blockIdx.x * 4 + w;
    const int rowTile = row >> 7;
    const unsigned short* cr = C + (size_t)row * N;
    if (lane == 0) { acnt[w] = 0; scnt[w] = 0; }

    const ushort2 su = *(const ushort2*)(rowmaxG + (size_t)row * NSTRIP + lane * 2);
    const float s0v = b2f(su.x), s1v = b2f(su.y);

    float a = s0v, b = s1v;
    float m5 = -1e30f;
#pragma unroll
    for (int s = 0; s < 5; ++s) {
        float mx = fmaxf(a, b);
#pragma unroll
        for (int m = 32; m > 0; m >>= 1) mx = fmaxf(mx, __shfl_xor(mx, m, 64));
        m5 = mx;
        const unsigned long long msk = __ballot(a == mx || b == mx);
        const int first = __ffsll(msk) - 1;
        if (lane == first) {
            if (a == mx) a = -1e30f;
            else b = -1e30f;
        }
    }
    const float thr = m5 - MARGIN;

    if (s0v >= thr) { const int p = atomicAdd(&acnt[w], 1); alist[w][p] = lane * 2; }
    if (s1v >= thr) { const int p = atomicAdd(&acnt[w], 1); alist[w][p] = lane * 2 + 1; }
    const int na = acnt[w];

    // one strip per wave-pass; 64 lanes cover the strip's 64 columns
    for (int g = 0; g < na; ++g) {
        const int s = alist[w][g];
        const int jg = s * 64 + lane;
        float v;
        if ((s >> 1) >= rowTile) {
            v = b2f(cr[jg]);                           // contiguous 128 B
        } else {
            v = b2f(C[(size_t)jg * N + row]);          // transposed gather (L3)
        }
        if (v >= thr) {
            const int p = atomicAdd(&scnt[w], 1);
            if (p < CCAP) sci[w][p] = jg;
        }
    }
    int nc = scnt[w];
    if (nc > CCAP) nc = CCAP;

    // exact fp32 rescore + lexicographic top-5
    const float4* xr = (const float4*)(X + (size_t)row * D);
    const float4 xa = xr[lane * 2];
    const float4 xb = xr[lane * 2 + 1];
    const float myinv = inv[row];
    float ev[1][5];
    int ei[1][5];
#pragma unroll
    for (int s = 0; s < 5; ++s) { ev[0][s] = -1e30f; ei[0][s] = 0x7fffffff; }
    for (int c = 0; c < nc; ++c) {
        const int cj = sci[w][c];
        const float4* yr = (const float4*)(X + (size_t)cj * D);
        const float4 ya = yr[lane * 2];
        const float4 yb = yr[lane * 2 + 1];
        float p = xa.x * ya.x + xa.y * ya.y + xa.z * ya.z + xa.w * ya.w +
                  xb.x * yb.x + xb.y * yb.y + xb.z * yb.z + xb.w * yb.w;
#pragma unroll
        for (int off = 32; off > 0; off >>= 1) p += __shfl_xor(p, off, 64);
        const float val = p * myinv * inv[cj];
        INS(ev, ei, 0, val, cj);
    }

    if (lane == 0) {
        float e[KSEL];
        float sum = 0.f;
#pragma unroll
        for (int s = 0; s < KSEL; ++s) {
            e[s] = expf((ev[0][s] - ev[0][0]) * TEMP_INV);
            sum += e[s];
        }
        const float invs = 1.0f / sum;
#pragma unroll
        for (int s = 0; s < KSEL; ++s) {
            const int ix = ei[0][s];
            if (ix >= 0 && ix < N) out[(size_t)row * N + ix] = e[s] * invs;
        }
    }
}

extern "C" void kernel_launch(void* const* d_in, const int* in_sizes, int n_in,
                              void* d_out, int out_size, void* d_ws, size_t ws_size,
                              hipStream_t stream) {
    const float* X = (const float*)d_in[0];
    float* out = (float*)d_out;
    // ws (1 GiB): Xb bf16 [8 MB] | inv [32 KB] | rowmax bf16 [2 MB] | C bf16 [128 MB @ +16 MB]
    unsigned short* Xb = (unsigned short*)d_ws;
    float* inv = (float*)(Xb + (size_t)N * D);
    unsigned short* rowmaxG = (unsigned short*)(inv + N);
    unsigned short* C = (unsigned short*)((char*)d_ws + (16u << 20));

    hipLaunchKernelGGL(prep_kernel, dim3(N), dim3(64), 0, stream, X, Xb, inv);
    hipLaunchKernelGGL(gemm_kernel, dim3(NBLK), dim3(256), 0, stream, Xb, C, rowmaxG, out);
    hipLaunchKernelGGL(scanfin_kernel, dim3(N / 4), dim3(256), 0, stream, C, rowmaxG, X, inv,
                       out);
}

// Round 12
// 395.683 us; speedup vs baseline: 1.2569x; 1.0870x over previous
//
#include <hip/hip_runtime.h>
#include <math.h>

#define N 8192
#define D 512
#define KSEL 5
#define TEMP_INV 10.0f
#define MARGIN 0.012f
#define CCAP 64
#define BK 64
#define CPITCH 136  // epilogue C-stage pitch in shorts (R5-proven)
#define NSTRIP 128  // 64-col strips per row
#define NTILE 64
#define NBLK (NTILE * (NTILE + 1) / 2)  // 2080 upper-triangle tiles

using short8 = __attribute__((ext_vector_type(8))) short;
using floatx4 = __attribute__((ext_vector_type(4))) float;

// Lexicographic top-5 insert: (value desc, index asc) — matches lax.top_k.
#define INS(TV, TIX, RI, VV, JJ)                                                     \
  {                                                                                  \
    const float _v = (VV);                                                           \
    const int _j = (JJ);                                                             \
    const bool _b4 = (_v > TV[RI][4]) || (_v == TV[RI][4] && _j < TIX[RI][4]);       \
    if (_b4) {                                                                       \
      const bool _b0 = (_v > TV[RI][0]) || (_v == TV[RI][0] && _j < TIX[RI][0]);     \
      const bool _b1 = (_v > TV[RI][1]) || (_v == TV[RI][1] && _j < TIX[RI][1]);     \
      const bool _b2 = (_v > TV[RI][2]) || (_v == TV[RI][2] && _j < TIX[RI][2]);     \
      const bool _b3 = (_v > TV[RI][3]) || (_v == TV[RI][3] && _j < TIX[RI][3]);     \
      TV[RI][4] = _b3 ? TV[RI][3] : _v;                                              \
      TIX[RI][4] = _b3 ? TIX[RI][3] : _j;                                            \
      TV[RI][3] = _b2 ? TV[RI][2] : (_b3 ? _v : TV[RI][3]);                          \
      TIX[RI][3] = _b2 ? TIX[RI][2] : (_b3 ? _j : TIX[RI][3]);                       \
      TV[RI][2] = _b1 ? TV[RI][1] : (_b2 ? _v : TV[RI][2]);                          \
      TIX[RI][2] = _b1 ? TIX[RI][1] : (_b2 ? _j : TIX[RI][2]);                       \
      TV[RI][1] = _b0 ? TV[RI][0] : (_b1 ? _v : TV[RI][1]);                          \
      TIX[RI][1] = _b0 ? TIX[RI][0] : (_b1 ? _j : TIX[RI][1]);                       \
      TV[RI][0] = _b0 ? _v : TV[RI][0];                                              \
      TIX[RI][0] = _b0 ? _j : TIX[RI][0];                                            \
    }                                                                                \
  }

__device__ inline unsigned short f2b(float f) {  // fp32 -> bf16 RNE (monotone)
    unsigned int u = __float_as_uint(f);
    unsigned int r = (u + 0x7FFFu + ((u >> 16) & 1u)) >> 16;
    return (unsigned short)r;
}
__device__ inline float b2f(unsigned short u) {
    return __uint_as_float(((unsigned int)u) << 16);
}

__device__ inline void gload_lds16(const unsigned short* g, unsigned short* l) {
    __builtin_amdgcn_global_load_lds((__attribute__((address_space(1))) void*)g,
                                     (__attribute__((address_space(3))) void*)l, 16, 0, 0);
}

// ---------------- Kernel 1: norms + bf16 normalized rows -----------------
__global__ __launch_bounds__(64) void prep_kernel(const float* __restrict__ X,
                                                  unsigned short* __restrict__ Xb,
                                                  float* __restrict__ inv) {
    const int row = blockIdx.x;
    const int t = threadIdx.x;
    const float4* xr = (const float4*)(X + (size_t)row * D);
    const float4 a = xr[t];
    const float4 b = xr[t + 64];
    float ss = a.x * a.x + a.y * a.y + a.z * a.z + a.w * a.w +
               b.x * b.x + b.y * b.y + b.z * b.z + b.w * b.w;
#pragma unroll
    for (int off = 32; off > 0; off >>= 1) ss += __shfl_xor(ss, off, 64);
    const float iv = 1.0f / fmaxf(sqrtf(ss), 1e-12f);
    if (t == 0) inv[row] = iv;
    ushort4 ua, ub;
    ua.x = f2b(a.x * iv); ua.y = f2b(a.y * iv); ua.z = f2b(a.z * iv); ua.w = f2b(a.w * iv);
    ub.x = f2b(b.x * iv); ub.y = f2b(b.y * iv); ub.z = f2b(b.z * iv); ub.w = f2b(b.w * iv);
    ((ushort4*)(Xb + (size_t)row * D))[t] = ua;
    ((ushort4*)(Xb + (size_t)row * D))[t + 64] = ub;
}

// ---------------- Kernel 2: symmetric bf16 MFMA GEMM ---------------------
// Upper-triangle tile (tib <= tjb) per block; writes tile + mirror, and
// strip-maxes for both row-sets. (Best-measured config, R8: 395 µs total.)
__global__ __launch_bounds__(256) void gemm_kernel(const unsigned short* __restrict__ Xb,
                                                   unsigned short* __restrict__ Cout,
                                                   unsigned short* __restrict__ rowmaxG) {
    __shared__ unsigned short smem[128 * CPITCH];  // 34.8 KB (A|B 32 KB, then Cs)
    unsigned short* Asm = smem;
    unsigned short* Bsm = smem + 8192;
    const int tid = threadIdx.x;
    const int w = tid >> 6;
    const int lane = tid & 63;
    const int wr = w >> 1, wc = w & 1;

    // decode upper-triangle pair: off(ti) = ti*(129-ti)/2
    const int t = (int)blockIdx.x;
    int tib = (int)((129.0 - sqrt(129.0 * 129.0 - 8.0 * (double)t)) * 0.5);
    while ((tib + 1) * (129 - (tib + 1)) / 2 <= t) ++tib;
    while (tib * (129 - tib) / 2 > t) --tib;
    const int tjb = tib + (t - tib * (129 - tib) / 2);
    const int i0 = tib * 128, j0 = tjb * 128;

    floatx4 acc[4][4];
#pragma unroll
    for (int ti = 0; ti < 4; ++ti)
#pragma unroll
        for (int tj = 0; tj < 4; ++tj) acc[ti][tj] = (floatx4){0.f, 0.f, 0.f, 0.f};

    const unsigned short* gA[4];
    const unsigned short* gB[4];
    unsigned short* lA[4];
    unsigned short* lB[4];
#pragma unroll
    for (int p = 0; p < 4; ++p) {
        const int slot = p * 256 + tid;
        const int row = slot >> 3;
        const int kq = (slot & 7) ^ (row & 7);
        gA[p] = Xb + (size_t)(i0 + row) * D + kq * 8;
        gB[p] = Xb + (size_t)(j0 + row) * D + kq * 8;
        lA[p] = Asm + slot * 8;
        lB[p] = Bsm + slot * 8;
    }

    const int r = lane & 15;
    const int q = lane >> 4;
    const int aRow0 = wr * 64 + r;
    const int bRow0 = wc * 64 + r;
    const int rx = r & 7;

#pragma unroll
    for (int p = 0; p < 4; ++p) {
        gload_lds16(gA[p], lA[p]);
        gload_lds16(gB[p], lB[p]);
    }

    for (int kc = 0; kc < D / BK; ++kc) {
        __syncthreads();
        short8 af[2][4], bf[2][4];
#pragma unroll
        for (int tt = 0; tt < 2; ++tt)
#pragma unroll
            for (int ti = 0; ti < 4; ++ti) {
                af[tt][ti] = *(const short8*)(Asm +
                    ((aRow0 + ti * 16) * 8 + ((tt * 4 + q) ^ rx)) * 8);
                bf[tt][ti] = *(const short8*)(Bsm +
                    ((bRow0 + ti * 16) * 8 + ((tt * 4 + q) ^ rx)) * 8);
            }
        __syncthreads();
        if (kc < D / BK - 1) {
            const int o = (kc + 1) * BK;
#pragma unroll
            for (int p = 0; p < 4; ++p) {
                gload_lds16(gA[p] + o, lA[p]);
                gload_lds16(gB[p] + o, lB[p]);
            }
        }
#pragma unroll
        for (int tt = 0; tt < 2; ++tt)
#pragma unroll
            for (int ti = 0; ti < 4; ++ti)
#pragma unroll
                for (int tj = 0; tj < 4; ++tj)
                    acc[ti][tj] = __builtin_amdgcn_mfma_f32_16x16x32_bf16(
                        af[tt][ti], bf[tt][tj], acc[ti][tj], 0, 0, 0);
    }

    // ---- A-side strip maxima: rows i0.., strip tjb*2 + wc ----
    {
        float rmax[16];
#pragma unroll
        for (int ti = 0; ti < 4; ++ti)
#pragma unroll
            for (int reg = 0; reg < 4; ++reg) {
                const float m0 = fmaxf(acc[ti][0][reg], acc[ti][1][reg]);
                const float m1 = fmaxf(acc[ti][2][reg], acc[ti][3][reg]);
                rmax[ti * 4 + reg] = fmaxf(m0, m1);
            }
#pragma unroll
        for (int k = 0; k < 16; ++k)
#pragma unroll
            for (int m = 1; m < 16; m <<= 1)
                rmax[k] = fmaxf(rmax[k], __shfl_xor(rmax[k], m, 64));
        if (r == 0) {
            const int strip = tjb * 2 + wc;
#pragma unroll
            for (int ti = 0; ti < 4; ++ti)
#pragma unroll
                for (int reg = 0; reg < 4; ++reg)
                    rowmaxG[(size_t)(i0 + wr * 64 + ti * 16 + q * 4 + reg) * NSTRIP +
                            strip] = f2b(rmax[ti * 4 + reg]);
        }
    }

    // ---- B-side strip maxima (mirror): rows j0.., strip tib*2 + wr ----
    if (tib != tjb) {
        float cmax[4];
#pragma unroll
        for (int tj = 0; tj < 4; ++tj) {
            float m = -1e30f;
#pragma unroll
            for (int ti = 0; ti < 4; ++ti)
#pragma unroll
                for (int reg = 0; reg < 4; ++reg) m = fmaxf(m, acc[ti][tj][reg]);
            m = fmaxf(m, __shfl_xor(m, 16, 64));
            m = fmaxf(m, __shfl_xor(m, 32, 64));
            cmax[tj] = m;
        }
        if (q == 0) {
#pragma unroll
            for (int tj = 0; tj < 4; ++tj)
                rowmaxG[(size_t)(j0 + wc * 64 + tj * 16 + r) * NSTRIP + tib * 2 + wr] =
                    f2b(cmax[tj]);
        }
    }

    // ---- epilogue: LDS restage -> coalesced bf16 C writes ----
    __syncthreads();
    unsigned short* Cs = smem;
#pragma unroll
    for (int ti = 0; ti < 4; ++ti)
#pragma unroll
        for (int tj = 0; tj < 4; ++tj)
#pragma unroll
            for (int reg = 0; reg < 4; ++reg) {
                const int rowl = wr * 64 + ti * 16 + q * 4 + reg;
                const int coll = wc * 64 + tj * 16 + r;
                Cs[rowl * CPITCH + (coll ^ ((rowl & 7) << 3))] = f2b(acc[ti][tj][reg]);
            }
    __syncthreads();
#pragma unroll
    for (int p = 0; p < 8; ++p) {
        const int id = p * 256 + tid;
        const int rw = id >> 4;
        const int c = id & 15;
        const int cc = c ^ (rw & 7);
        const int4 v = *(const int4*)&Cs[rw * CPITCH + cc * 8];
        *(int4*)&Cout[(size_t)(i0 + rw) * N + j0 + c * 8] = v;
    }

    // ---- mirror tile: C[j0..][i0..] = tile^T ----
    if (tib != tjb) {
        __syncthreads();  // all Cs reads above complete
#pragma unroll
        for (int ti = 0; ti < 4; ++ti)
#pragma unroll
            for (int tj = 0; tj < 4; ++tj)
#pragma unroll
                for (int reg = 0; reg < 4; ++reg) {
                    const int rowl = wr * 64 + ti * 16 + q * 4 + reg;
                    const int coll = wc * 64 + tj * 16 + r;
                    Cs[coll * CPITCH + (rowl ^ ((coll & 7) << 3))] = f2b(acc[ti][tj][reg]);
                }
        __syncthreads();
#pragma unroll
        for (int p = 0; p < 8; ++p) {
            const int id = p * 256 + tid;
            const int rw = id >> 4;
            const int c = id & 15;
            const int cc = c ^ (rw & 7);
            const int4 v = *(const int4*)&Cs[rw * CPITCH + cc * 8];
            *(int4*)&Cout[(size_t)(j0 + rw) * N + i0 + c * 8] = v;
        }
    }
}

// ---------------- Kernel 3: stripmax-guided candidates + rescore + out ---
__global__ __launch_bounds__(256) void scanfin_kernel(const unsigned short* __restrict__ C,
                                                      const unsigned short* __restrict__ rowmaxG,
                                                      const float* __restrict__ X,
                                                      const float* __restrict__ inv,
                                                      float* __restrict__ out) {
    __shared__ int acnt[4];
    __shared__ int alist[4][NSTRIP];
    __shared__ int scnt[4];
    __shared__ int sci[4][CCAP];
    const int tid = threadIdx.x;
    const int w = tid >> 6;
    const int lane = tid & 63;
    const int row = (int)blockIdx.x * 4 + w;
    const unsigned short* cr = C + (size_t)row * N;
    if (lane == 0) { acnt[w] = 0; scnt[w] = 0; }

    const ushort2 su = *(const ushort2*)(rowmaxG + (size_t)row * NSTRIP + lane * 2);
    const float s0v = b2f(su.x), s1v = b2f(su.y);

    float a = s0v, b = s1v;
    float m5 = -1e30f;
#pragma unroll
    for (int s = 0; s < 5; ++s) {
        float mx = fmaxf(a, b);
#pragma unroll
        for (int m = 32; m > 0; m >>= 1) mx = fmaxf(mx, __shfl_xor(mx, m, 64));
        m5 = mx;
        const unsigned long long msk = __ballot(a == mx || b == mx);
        const int first = __ffsll(msk) - 1;
        if (lane == first) {
            if (a == mx) a = -1e30f;
            else b = -1e30f;
        }
    }
    const float thr = m5 - MARGIN;

    if (s0v >= thr) { const int p = atomicAdd(&acnt[w], 1); alist[w][p] = lane * 2; }
    if (s1v >= thr) { const int p = atomicAdd(&acnt[w], 1); alist[w][p] = lane * 2 + 1; }
    const int na = acnt[w];

    for (int g = 0; g < na; g += 2) {
        const int s = (lane < 32) ? alist[w][g] : ((g + 1 < na) ? alist[w][g + 1] : -1);
        if (s >= 0) {
            const int jb = s * 64 + (lane & 31) * 2;
            const ushort2 u = *(const ushort2*)(cr + jb);
            const float v0 = b2f(u.x), v1 = b2f(u.y);
            if (v0 >= thr) { const int p = atomicAdd(&scnt[w], 1); if (p < CCAP) sci[w][p] = jb; }
            if (v1 >= thr) { const int p = atomicAdd(&scnt[w], 1); if (p < CCAP) sci[w][p] = jb + 1; }
        }
    }
    int nc = scnt[w];
    if (nc > CCAP) nc = CCAP;

    const float4* xr = (const float4*)(X + (size_t)row * D);
    const float4 xa = xr[lane * 2];
    const float4 xb = xr[lane * 2 + 1];
    const float myinv = inv[row];
    float ev[1][5];
    int ei[1][5];
#pragma unroll
    for (int s = 0; s < 5; ++s) { ev[0][s] = -1e30f; ei[0][s] = 0x7fffffff; }
    for (int c = 0; c < nc; ++c) {
        const int cj = sci[w][c];
        const float4* yr = (const float4*)(X + (size_t)cj * D);
        const float4 ya = yr[lane * 2];
        const float4 yb = yr[lane * 2 + 1];
        float p = xa.x * ya.x + xa.y * ya.y + xa.z * ya.z + xa.w * ya.w +
                  xb.x * yb.x + xb.y * yb.y + xb.z * yb.z + xb.w * yb.w;
#pragma unroll
        for (int off = 32; off > 0; off >>= 1) p += __shfl_xor(p, off, 64);
        const float val = p * myinv * inv[cj];
        INS(ev, ei, 0, val, cj);
    }

    float4* orow = (float4*)(out + (size_t)row * N);
    const float4 z = make_float4(0.f, 0.f, 0.f, 0.f);
    for (int it = lane; it < N / 4; it += 64) orow[it] = z;
    __syncthreads();

    if (lane == 0) {
        float e[KSEL];
        float sum = 0.f;
#pragma unroll
        for (int s = 0; s < KSEL; ++s) {
            e[s] = expf((ev[0][s] - ev[0][0]) * TEMP_INV);
            sum += e[s];
        }
        const float invs = 1.0f / sum;
#pragma unroll
        for (int s = 0; s < KSEL; ++s) {
            const int ix = ei[0][s];
            if (ix >= 0 && ix < N) out[(size_t)row * N + ix] = e[s] * invs;
        }
    }
}

extern "C" void kernel_launch(void* const* d_in, const int* in_sizes, int n_in,
                              void* d_out, int out_size, void* d_ws, size_t ws_size,
                              hipStream_t stream) {
    const float* X = (const float*)d_in[0];
    float* out = (float*)d_out;
    // ws (1 GiB): Xb bf16 [8 MB] | inv [32 KB] | rowmax bf16 [2 MB] | C bf16 [128 MB @ +16 MB]
    unsigned short* Xb = (unsigned short*)d_ws;
    float* inv = (float*)(Xb + (size_t)N * D);
    unsigned short* rowmaxG = (unsigned short*)(inv + N);
    unsigned short* C = (unsigned short*)((char*)d_ws + (16u << 20));

    hipLaunchKernelGGL(prep_kernel, dim3(N), dim3(64), 0, stream, X, Xb, inv);
    hipLaunchKernelGGL(gemm_kernel, dim3(NBLK), dim3(256), 0, stream, Xb, C, rowmaxG);
    hipLaunchKernelGGL(scanfin_kernel, dim3(N / 4), dim3(256), 0, stream, C, rowmaxG, X, inv,
                       out);
}